// Round 5
// baseline (184.307 us; speedup 1.0000x reference)
//
#include <hip/hip_runtime.h>

#define HH 128
#define NT 512
#define PT 256

typedef float  f32x4  __attribute__((ext_vector_type(4)));
typedef short  bf16x8 __attribute__((ext_vector_type(8)));

static __device__ __forceinline__ unsigned short bf16_rne(float f){
  unsigned int u = __float_as_uint(f);
  unsigned int r = u + 0x7fffu + ((u >> 16) & 1u);
  return (unsigned short)(r >> 16);
}
static __device__ __forceinline__ unsigned short bf16_trunc(float f){
  return (unsigned short)(__float_as_uint(f) >> 16);
}
static __device__ __forceinline__ float bf16_to_f(unsigned short s){
  return __uint_as_float(((unsigned int)s) << 16);
}

// fast saturating sigmoid/tanh via v_exp_f32 + v_rcp_f32
__device__ __forceinline__ float sigf(float x){
  float t = __builtin_amdgcn_exp2f(-1.44269504089f * x);
  return __builtin_amdgcn_rcpf(1.f + t);
}
__device__ __forceinline__ float tanhf_(float x){
  float t = __builtin_amdgcn_exp2f(2.88539008178f * x);
  return 1.f - 2.f*__builtin_amdgcn_rcpf(t + 1.f);
}

// Pack W into MFMA-B-fragment order, split bf16 hi/lo.
// Pack index: (((wp*8 + q*2 + ft)*4 + kc)*64 + lane)*8 + j
//   g = q*128 + wp*32 + ft*16 + (lane&15);  k = kc*32 + (lane>>4)*8 + j
__global__ __launch_bounds__(PT) void prep_pack(
    const float* __restrict__ W,
    unsigned short* __restrict__ pEh, unsigned short* __restrict__ pEl,
    unsigned short* __restrict__ pLh, unsigned short* __restrict__ pLl)
{
  int idx = blockIdx.x*PT + threadIdx.x;     // 0..8191
  int l  = idx & 63;
  int kc = (idx >> 6) & 3;
  int gl = (idx >> 8) & 7;
  int wp = (idx >> 11);                      // 0..3
  int q  = gl >> 1, ft = gl & 1;
  int g  = q*128 + wp*32 + ft*16 + (l & 15);
  int kbase = kc*32 + (l >> 4)*8;

  unsigned short eh[8], el[8], lh[8], ll[8];
#pragma unroll
  for (int j = 0; j < 8; ++j){
    int k = kbase + j;
    float w0 = W[g*256 + k];
    float w1 = W[g*256 + 128 + k];
    float we = w0 + 0.5f*w1;
    unsigned short h0 = bf16_rne(we);
    eh[j] = h0; el[j] = bf16_trunc(we - bf16_to_f(h0));
    unsigned short h1 = bf16_rne(w1);
    lh[j] = h1; ll[j] = bf16_trunc(w1 - bf16_to_f(h1));
  }
  long base = (long)idx*8;
  *(bf16x8*)&pEh[base] = *(bf16x8*)eh;
  *(bf16x8*)&pEl[base] = *(bf16x8*)el;
  *(bf16x8*)&pLh[base] = *(bf16x8*)lh;
  *(bf16x8*)&pLl[base] = *(bf16x8*)ll;
}

// Multi-level tree block kernel.
// LEAF=1: stage ROWS0=64 leaf x rows (fp32). LEAF=0: stage 2*ROWS0 children,
// pair-summed (h->Asum, c->Csum). Then NLEV levels in LDS; each level:
// tiles of 16 A-rows, MFMA vs register-resident B (split-bf16 x3),
// LSTM epilogue stashed in regs, pair-sums written to Asum/Csum post-barrier.
// Last level writes 16 nodes (h,c) to global, or root h if FINAL.
template<int LEAF, int ROWS0, int NLEV, int FINAL>
__global__ __launch_bounds__(NT, 2) void treeblk(
    const float* __restrict__ h_in, const float* __restrict__ c_in,
    const unsigned short* __restrict__ pB0h, const unsigned short* __restrict__ pB0l,
    const unsigned short* __restrict__ pB1h, const unsigned short* __restrict__ pB1l,
    const float* __restrict__ bias,
    float* __restrict__ h_out, float* __restrict__ c_out)
{
  constexpr int CROWS = LEAF ? (ROWS0/2) : ROWS0;
  __shared__ float Asum[ROWS0][132];   // A rows (already pair-summed h / leaf x), fp32
  __shared__ float Csum[CROWS][132];   // cc rows (pair-summed c), fp32

  const int t = threadIdx.x;
  const long blk = blockIdx.x;
  const int w = t >> 6, l = t & 63;
  const int a = l >> 4;          // 0..3
  const int fcol = l & 15;
  const int feat = w*16 + fcol;

  // ---- stage ----
  if constexpr (LEAF){
    int row = t >> 3, c0 = (t & 7)*16;
    long g = ((long)blk*64 + row)*HH + c0;
#pragma unroll
    for (int i = 0; i < 4; ++i)
      *(float4*)&Asum[row][c0 + 4*i] = *(const float4*)&h_in[g + 4*i];
  } else if constexpr (ROWS0 == 64){
    int row = t >> 3, c0 = (t & 7)*16;
    long g = ((long)blk*128 + 2*row)*HH + c0;
#pragma unroll
    for (int i = 0; i < 4; ++i){
      float4 x = *(const float4*)&h_in[g + 4*i];
      float4 y = *(const float4*)&h_in[g + HH + 4*i];
      float4 s; s.x = x.x+y.x; s.y = x.y+y.y; s.z = x.z+y.z; s.w = x.w+y.w;
      *(float4*)&Asum[row][c0 + 4*i] = s;
      float4 cx = *(const float4*)&c_in[g + 4*i];
      float4 cy = *(const float4*)&c_in[g + HH + 4*i];
      float4 cs; cs.x = cx.x+cy.x; cs.y = cx.y+cy.y; cs.z = cx.z+cy.z; cs.w = cx.w+cy.w;
      *(float4*)&Csum[row][c0 + 4*i] = cs;
    }
  } else {  // ROWS0 == 32
    int row = t >> 4, c0 = (t & 15)*8;
    long g = ((long)blk*64 + 2*row)*HH + c0;
#pragma unroll
    for (int i = 0; i < 2; ++i){
      float4 x = *(const float4*)&h_in[g + 4*i];
      float4 y = *(const float4*)&h_in[g + HH + 4*i];
      float4 s; s.x = x.x+y.x; s.y = x.y+y.y; s.z = x.z+y.z; s.w = x.w+y.w;
      *(float4*)&Asum[row][c0 + 4*i] = s;
      float4 cx = *(const float4*)&c_in[g + 4*i];
      float4 cy = *(const float4*)&c_in[g + HH + 4*i];
      float4 cs; cs.x = cx.x+cy.x; cs.y = cx.y+cy.y; cs.z = cx.z+cy.z; cs.w = cx.w+cy.w;
      *(float4*)&Csum[row][c0 + 4*i] = cs;
    }
  }

  // ---- register-resident B (level-0 set) + bias ----
  bf16x8 rbH[4][4], rbL[4][4];
#pragma unroll
  for (int q = 0; q < 4; ++q)
#pragma unroll
    for (int kc = 0; kc < 4; ++kc){
      long off = ((long)((((w>>1)*8) + q*2 + (w&1))*4 + kc)*64 + l)*8;
      rbH[q][kc] = *(const bf16x8*)&pB0h[off];
      rbL[q][kc] = *(const bf16x8*)&pB0l[off];
    }
  float B4[4];
#pragma unroll
  for (int q = 0; q < 4; ++q) B4[q] = bias[q*HH + feat];

  __syncthreads();

#pragma unroll
  for (int lv = 0; lv < NLEV; ++lv){
    const int rows  = ROWS0 >> lv;
    const int tiles = (rows >= 16) ? (rows/16) : 1;
    float hv[4][4], cv[4][4];

#pragma unroll
    for (int mt = 0; mt < 4; ++mt){
      if (mt >= tiles) continue;
      // A-build: read summed fp32 rows, trunc-split to bf16 hi/lo via v_perm
      bf16x8 aH[4], aL[4];
#pragma unroll
      for (int kc = 0; kc < 4; ++kc){
        const float* ap = &Asum[mt*16 + fcol][kc*32 + a*8];
        float av[8];
        *(float4*)&av[0] = *(const float4*)&ap[0];
        *(float4*)&av[4] = *(const float4*)&ap[4];
        unsigned int hp[4], lp[4];
#pragma unroll
        for (int p = 0; p < 4; ++p){
          unsigned int u0 = __float_as_uint(av[2*p]);
          unsigned int u1 = __float_as_uint(av[2*p+1]);
          float l0 = av[2*p]   - __uint_as_float(u0 & 0xffff0000u);
          float l1 = av[2*p+1] - __uint_as_float(u1 & 0xffff0000u);
          hp[p] = __builtin_amdgcn_perm(u1, u0, 0x07060302u);
          lp[p] = __builtin_amdgcn_perm(__float_as_uint(l1), __float_as_uint(l0), 0x07060302u);
        }
        uint4 hq = {hp[0], hp[1], hp[2], hp[3]};
        uint4 lq = {lp[0], lp[1], lp[2], lp[3]};
        aH[kc] = *(bf16x8*)&hq;
        aL[kc] = *(bf16x8*)&lq;
      }
      // MFMA (3x split)
      f32x4 acc[4];
#pragma unroll
      for (int q = 0; q < 4; ++q) acc[q] = (f32x4)(0.f);
#pragma unroll
      for (int kc = 0; kc < 4; ++kc)
#pragma unroll
        for (int q = 0; q < 4; ++q){
          acc[q] = __builtin_amdgcn_mfma_f32_16x16x32_bf16(aH[kc], rbH[q][kc], acc[q], 0, 0, 0);
          acc[q] = __builtin_amdgcn_mfma_f32_16x16x32_bf16(aH[kc], rbL[q][kc], acc[q], 0, 0, 0);
          acc[q] = __builtin_amdgcn_mfma_f32_16x16x32_bf16(aL[kc], rbH[q][kc], acc[q], 0, 0, 0);
        }
      // epilogue -> register stash
#pragma unroll
      for (int rr = 0; rr < 4; ++rr){
        int n = mt*16 + a*4 + rr;
        float cc = (LEAF && lv == 0) ? 0.f : Csum[n][feat];
        float fv = acc[0][rr] + B4[0];
        float iv = acc[1][rr] + B4[1];
        float gv = acc[2][rr] + B4[2];
        float ov = acc[3][rr] + B4[3];
        float c = sigf(fv)*cc + sigf(iv)*tanhf_(gv);
        float h = sigf(ov)*tanhf_(c);
        hv[mt][rr] = h; cv[mt][rr] = c;
      }
    }

    // leaf kernel: swap B to the effective (internal-node) weights after lvl 0
    if (LEAF && lv == 0){
#pragma unroll
      for (int q = 0; q < 4; ++q)
#pragma unroll
        for (int kc = 0; kc < 4; ++kc){
          long off = ((long)((((w>>1)*8) + q*2 + (w&1))*4 + kc)*64 + l)*8;
          rbH[q][kc] = *(const bf16x8*)&pB1h[off];
          rbL[q][kc] = *(const bf16x8*)&pB1l[off];
        }
    }

    __syncthreads();   // all Asum/Csum reads of this level complete

    if (lv < NLEV-1){
      // write pair-sums for next level (WAR-safe post-barrier)
#pragma unroll
      for (int mt = 0; mt < 4; ++mt){
        if (mt >= tiles) continue;
#pragma unroll
        for (int p = 0; p < 2; ++p){
          int prow = mt*8 + a*2 + p;
          Asum[prow][feat] = hv[mt][2*p] + hv[mt][2*p+1];
          Csum[prow][feat] = cv[mt][2*p] + cv[mt][2*p+1];
        }
      }
    } else if (FINAL){
      if (a == 0) h_out[feat] = hv[0][0];
    } else {
      long nb = blk*16;
#pragma unroll
      for (int rr = 0; rr < 4; ++rr){
        long n = nb + a*4 + rr;
        h_out[n*HH + feat] = hv[0][rr];
        c_out[n*HH + feat] = cv[0][rr];
      }
    }
    __syncthreads();
  }
}

extern "C" void kernel_launch(void* const* d_in, const int* in_sizes, int n_in,
                              void* d_out, int out_size, void* d_ws, size_t ws_size,
                              hipStream_t stream){
  const float* leaf = (const float*)d_in[0];   // 131072 x 128 f32
  const float* W    = (const float*)d_in[1];   // 512 x 256 f32
  const float* bias = (const float*)d_in[2];   // 512 f32
  float* out = (float*)d_out;                  // 128 f32

  unsigned short* pEh = (unsigned short*)d_ws;         // 4 x 65536 shorts
  unsigned short* pEl = pEh + 65536;
  unsigned short* pLh = pEl + 65536;
  unsigned short* pLl = pLh + 65536;
  float* h1 = (float*)(pLl + 65536);           // 2^15 x 128
  float* c1 = h1 + (long)(1<<15)*HH;
  float* h2 = c1 + (long)(1<<15)*HH;           // 2^12 x 128
  float* c2 = h2 + (long)(1<<12)*HH;
  float* h3 = c2 + (long)(1<<12)*HH;           // 512 x 128
  float* c3 = h3 + 512*HH;
  float* h4 = c3 + 512*HH;                     // 64 x 128
  float* c4 = h4 + 64*HH;

  prep_pack<<<32, PT, 0, stream>>>(W, pEh, pEl, pLh, pLl);

  // P1: 2^17 leaves -> 2^15 (3 levels/block, 64 leaves/block)
  treeblk<1,64,3,0><<<2048, NT, 0, stream>>>(leaf, nullptr, pLh, pLl, pEh, pEl, bias, h1, c1);
  // P2: 2^15 -> 2^12
  treeblk<0,64,3,0><<<256, NT, 0, stream>>>(h1, c1, pEh, pEl, pEh, pEl, bias, h2, c2);
  // P3: 2^12 -> 2^9
  treeblk<0,64,3,0><<<32, NT, 0, stream>>>(h2, c2, pEh, pEl, pEh, pEl, bias, h3, c3);
  // P4: 2^9 -> 2^6
  treeblk<0,64,3,0><<<4, NT, 0, stream>>>(h3, c3, pEh, pEl, pEh, pEl, bias, h4, c4);
  // P5: 64 -> root (6 levels, FINAL)
  treeblk<0,32,6,1><<<1, NT, 0, stream>>>(h4, c4, pEh, pEl, pEh, pEl, bias, out, nullptr);

  (void)in_sizes; (void)n_in; (void)out_size; (void)ws_size;
}

// Round 6
// 183.369 us; speedup vs baseline: 1.0051x; 1.0051x over previous
//
#include <hip/hip_runtime.h>

#define HH 128
#define NT 512
#define PT 256
#define GL 256   // leaf grid (grid-stride)

typedef float  f32x4  __attribute__((ext_vector_type(4)));
typedef short  bf16x8 __attribute__((ext_vector_type(8)));

static __device__ __forceinline__ unsigned short bf16_rne(float f){
  unsigned int u = __float_as_uint(f);
  unsigned int r = u + 0x7fffu + ((u >> 16) & 1u);
  return (unsigned short)(r >> 16);
}
static __device__ __forceinline__ unsigned short bf16_trunc(float f){
  return (unsigned short)(__float_as_uint(f) >> 16);
}
static __device__ __forceinline__ float bf16_to_f(unsigned short s){
  return __uint_as_float(((unsigned int)s) << 16);
}

// fast saturating sigmoid/tanh via v_exp_f32 + v_rcp_f32
__device__ __forceinline__ float sigf(float x){
  float t = __builtin_amdgcn_exp2f(-1.44269504089f * x);
  return __builtin_amdgcn_rcpf(1.f + t);
}
__device__ __forceinline__ float tanhf_(float x){
  float t = __builtin_amdgcn_exp2f(2.88539008178f * x);
  return 1.f - 2.f*__builtin_amdgcn_rcpf(t + 1.f);
}

// Pack W into MFMA-B-fragment order, split bf16 hi/lo.
// Pack index: (((wp*8 + q*2 + ft)*4 + kc)*64 + lane)*8 + j
//   g = q*128 + wp*32 + ft*16 + (lane&15);  k = kc*32 + (lane>>4)*8 + j
__global__ __launch_bounds__(PT) void prep_pack(
    const float* __restrict__ W,
    unsigned short* __restrict__ pEh, unsigned short* __restrict__ pEl,
    unsigned short* __restrict__ pLh, unsigned short* __restrict__ pLl)
{
  int idx = blockIdx.x*PT + threadIdx.x;     // 0..8191
  int l  = idx & 63;
  int kc = (idx >> 6) & 3;
  int gl = (idx >> 8) & 7;
  int wp = (idx >> 11);                      // 0..3
  int q  = gl >> 1, ft = gl & 1;
  int g  = q*128 + wp*32 + ft*16 + (l & 15);
  int kbase = kc*32 + (l >> 4)*8;

  unsigned short eh[8], el[8], lh[8], ll[8];
#pragma unroll
  for (int j = 0; j < 8; ++j){
    int k = kbase + j;
    float w0 = W[g*256 + k];
    float w1 = W[g*256 + 128 + k];
    float we = w0 + 0.5f*w1;
    unsigned short h0 = bf16_rne(we);
    eh[j] = h0; el[j] = bf16_trunc(we - bf16_to_f(h0));
    unsigned short h1 = bf16_rne(w1);
    lh[j] = h1; ll[j] = bf16_trunc(w1 - bf16_to_f(h1));
  }
  long base = (long)idx*8;
  *(bf16x8*)&pEh[base] = *(bf16x8*)eh;
  *(bf16x8*)&pEl[base] = *(bf16x8*)el;
  *(bf16x8*)&pLh[base] = *(bf16x8*)lh;
  *(bf16x8*)&pLl[base] = *(bf16x8*)ll;
}

// Leaf level (2^17 nodes). R4-style LDS dbuf staging of x, but:
//  - cc==0 => f-gate dead => skip q=0 (72 MFMA/tile instead of 96)
//  - part-major MFMA order (same-acc distance 6)
//  - output = pair-sum planes: hsum split bf16 hi/lo + csum fp32
__global__ __launch_bounds__(NT, 2) void leaf_mfma(
    const float* __restrict__ x_leaf,
    const unsigned short* __restrict__ packH, const unsigned short* __restrict__ packL,
    const float* __restrict__ bias,
    unsigned short* __restrict__ HpO, unsigned short* __restrict__ LpO,
    float* __restrict__ csO, int ntiles)
{
  __shared__ unsigned short AsH[2][32][HH+8];
  __shared__ unsigned short AsL[2][32][HH+8];

  const int t = threadIdx.x;
  const int w = t >> 6, l = t & 63;
  const int a = l >> 4, fcol = l & 15, feat = w*16 + fcol;

  bf16x8 rbH[4][4], rbL[4][4];
#pragma unroll
  for (int q = 1; q < 4; ++q)       // q=0 (f-gate) unused at leaf
#pragma unroll
    for (int kc = 0; kc < 4; ++kc){
      long off = ((long)((((w>>1)*8) + q*2 + (w&1))*4 + kc)*64 + l)*8;
      rbH[q][kc] = *(const bf16x8*)&packH[off];
      rbL[q][kc] = *(const bf16x8*)&packL[off];
    }
  float B4[4];
#pragma unroll
  for (int q = 1; q < 4; ++q) B4[q] = bias[q*HH + feat];

  auto stage = [&](int buf, int tile){
    int row = t >> 4;
    int ks  = (t & 15) * 8;
    long base = ((long)tile*32 + row)*HH + ks;
    float v[8];
    *(float4*)&v[0] = *(const float4*)&x_leaf[base];
    *(float4*)&v[4] = *(const float4*)&x_leaf[base + 4];
    unsigned short hh[8], ll[8];
#pragma unroll
    for (int j = 0; j < 8; ++j){
      unsigned short h0 = bf16_rne(v[j]);
      hh[j] = h0; ll[j] = bf16_trunc(v[j] - bf16_to_f(h0));
    }
    *(bf16x8*)&AsH[buf][row][ks] = *(bf16x8*)hh;
    *(bf16x8*)&AsL[buf][row][ks] = *(bf16x8*)ll;
  };

  int tile = blockIdx.x;
  if (tile < ntiles) stage(0, tile);
  __syncthreads();
  int buf = 0;

  for (; tile < ntiles; tile += GL){
    int nxt = tile + GL;
    if (nxt < ntiles) stage(buf^1, nxt);

    f32x4 acc[2][4];
#pragma unroll
    for (int mt = 0; mt < 2; ++mt)
#pragma unroll
      for (int q = 0; q < 4; ++q) acc[mt][q] = (f32x4)(0.f);

#pragma unroll
    for (int kc = 0; kc < 4; ++kc){
      bf16x8 aH[2], aL[2];
#pragma unroll
      for (int mt = 0; mt < 2; ++mt){
        int row = mt*16 + fcol;
        int co  = kc*32 + a*8;
        aH[mt] = *(const bf16x8*)&AsH[buf][row][co];
        aL[mt] = *(const bf16x8*)&AsL[buf][row][co];
      }
      // part-major: same-acc reuse distance = 6
#pragma unroll
      for (int q = 1; q < 4; ++q)
#pragma unroll
        for (int mt = 0; mt < 2; ++mt)
          acc[mt][q] = __builtin_amdgcn_mfma_f32_16x16x32_bf16(aH[mt], rbH[q][kc], acc[mt][q], 0, 0, 0);
#pragma unroll
      for (int q = 1; q < 4; ++q)
#pragma unroll
        for (int mt = 0; mt < 2; ++mt)
          acc[mt][q] = __builtin_amdgcn_mfma_f32_16x16x32_bf16(aH[mt], rbL[q][kc], acc[mt][q], 0, 0, 0);
#pragma unroll
      for (int q = 1; q < 4; ++q)
#pragma unroll
        for (int mt = 0; mt < 2; ++mt)
          acc[mt][q] = __builtin_amdgcn_mfma_f32_16x16x32_bf16(aL[mt], rbH[q][kc], acc[mt][q], 0, 0, 0);
    }

    // epilogue: leaf cell (cc=0): c = sig(i)*tanh(g); h = sig(o)*tanh(c)
#pragma unroll
    for (int mt = 0; mt < 2; ++mt){
      float hv[4], cv[4];
#pragma unroll
      for (int rr = 0; rr < 4; ++rr){
        float iv = acc[mt][1][rr] + B4[1];
        float gv = acc[mt][2][rr] + B4[2];
        float ov = acc[mt][3][rr] + B4[3];
        float c = sigf(iv)*tanhf_(gv);
        float h = sigf(ov)*tanhf_(c);
        hv[rr] = h; cv[rr] = c;
      }
#pragma unroll
      for (int p = 0; p < 2; ++p){
        float hs = hv[2*p] + hv[2*p+1];
        float c2 = cv[2*p] + cv[2*p+1];
        long prow = (long)tile*16 + mt*8 + a*2 + p;
        unsigned short hi = bf16_rne(hs);
        unsigned short lo = bf16_trunc(hs - bf16_to_f(hi));
        HpO[prow*HH + feat] = hi;
        LpO[prow*HH + feat] = lo;
        csO[prow*HH + feat] = c2;
      }
    }
    __syncthreads();
    buf ^= 1;
  }
}

// Internal level, barrier-free, LDS-free. Input = pair-sum planes
// (Hp/Lp bf16 split + cs fp32, one row per node). A-fragments loaded
// directly from the planes; B register-resident; part-major MFMA.
__global__ __launch_bounds__(NT, 2) void int_mfma(
    const unsigned short* __restrict__ Hp, const unsigned short* __restrict__ Lp,
    const float* __restrict__ cs,
    const unsigned short* __restrict__ packH, const unsigned short* __restrict__ packL,
    const float* __restrict__ bias,
    unsigned short* __restrict__ HpO, unsigned short* __restrict__ LpO,
    float* __restrict__ csO, int ntiles)
{
  const int t = threadIdx.x;
  const int w = t >> 6, l = t & 63;
  const int a = l >> 4, fcol = l & 15, feat = w*16 + fcol;

  bf16x8 rbH[4][4], rbL[4][4];
#pragma unroll
  for (int q = 0; q < 4; ++q)
#pragma unroll
    for (int kc = 0; kc < 4; ++kc){
      long off = ((long)((((w>>1)*8) + q*2 + (w&1))*4 + kc)*64 + l)*8;
      rbH[q][kc] = *(const bf16x8*)&packH[off];
      rbL[q][kc] = *(const bf16x8*)&packL[off];
    }
  float B4[4];
#pragma unroll
  for (int q = 0; q < 4; ++q) B4[q] = bias[q*HH + feat];

  for (int tile = blockIdx.x; tile < ntiles; tile += gridDim.x){
    // A fragments direct from planes (16B per lane; wave covers 16 rows x 64B)
    bf16x8 aH[4][2], aL[4][2];
#pragma unroll
    for (int kc = 0; kc < 4; ++kc)
#pragma unroll
      for (int mt = 0; mt < 2; ++mt){
        long off = ((long)tile*32 + mt*16 + fcol)*HH + kc*32 + a*8;
        aH[kc][mt] = *(const bf16x8*)&Hp[off];
        aL[kc][mt] = *(const bf16x8*)&Lp[off];
      }
    // cc loads issued early; latency hides under MFMA
    float cc[2][4];
#pragma unroll
    for (int mt = 0; mt < 2; ++mt)
#pragma unroll
      for (int rr = 0; rr < 4; ++rr)
        cc[mt][rr] = cs[((long)tile*32 + mt*16 + a*4 + rr)*HH + feat];

    f32x4 acc[2][4];
#pragma unroll
    for (int mt = 0; mt < 2; ++mt)
#pragma unroll
      for (int q = 0; q < 4; ++q) acc[mt][q] = (f32x4)(0.f);

#pragma unroll
    for (int kc = 0; kc < 4; ++kc){
#pragma unroll
      for (int q = 0; q < 4; ++q)
#pragma unroll
        for (int mt = 0; mt < 2; ++mt)
          acc[mt][q] = __builtin_amdgcn_mfma_f32_16x16x32_bf16(aH[kc][mt], rbH[q][kc], acc[mt][q], 0, 0, 0);
#pragma unroll
      for (int q = 0; q < 4; ++q)
#pragma unroll
        for (int mt = 0; mt < 2; ++mt)
          acc[mt][q] = __builtin_amdgcn_mfma_f32_16x16x32_bf16(aH[kc][mt], rbL[q][kc], acc[mt][q], 0, 0, 0);
#pragma unroll
      for (int q = 0; q < 4; ++q)
#pragma unroll
        for (int mt = 0; mt < 2; ++mt)
          acc[mt][q] = __builtin_amdgcn_mfma_f32_16x16x32_bf16(aL[kc][mt], rbH[q][kc], acc[mt][q], 0, 0, 0);
    }

#pragma unroll
    for (int mt = 0; mt < 2; ++mt){
      float hv[4], cv[4];
#pragma unroll
      for (int rr = 0; rr < 4; ++rr){
        float fv = acc[mt][0][rr] + B4[0];
        float iv = acc[mt][1][rr] + B4[1];
        float gv = acc[mt][2][rr] + B4[2];
        float ov = acc[mt][3][rr] + B4[3];
        float c = sigf(fv)*cc[mt][rr] + sigf(iv)*tanhf_(gv);
        float h = sigf(ov)*tanhf_(c);
        hv[rr] = h; cv[rr] = c;
      }
#pragma unroll
      for (int p = 0; p < 2; ++p){
        float hs = hv[2*p] + hv[2*p+1];
        float c2 = cv[2*p] + cv[2*p+1];
        long prow = (long)tile*16 + mt*8 + a*2 + p;
        unsigned short hi = bf16_rne(hs);
        unsigned short lo = bf16_trunc(hs - bf16_to_f(hi));
        HpO[prow*HH + feat] = hi;
        LpO[prow*HH + feat] = lo;
        csO[prow*HH + feat] = c2;
      }
    }
  }
}

// Multi-level tail block. INPLANES=1: stage ROWS0 pair-rows from planes.
// INPLANES=0: stage 2*ROWS0 raw h,c rows pair-summed. Then NLEV levels in
// LDS. FINAL=1 writes root h; else raw h,c (1 node per block).
template<int ROWS0, int NLEV, int INPLANES, int FINAL>
__global__ __launch_bounds__(NT, 2) void treeblk2(
    const unsigned short* __restrict__ Hp, const unsigned short* __restrict__ Lp,
    const float* __restrict__ cs,
    const float* __restrict__ hraw, const float* __restrict__ craw,
    const unsigned short* __restrict__ packH, const unsigned short* __restrict__ packL,
    const float* __restrict__ bias,
    float* __restrict__ h_out, float* __restrict__ c_out,
    float* __restrict__ root_out)
{
  constexpr int MT = ROWS0/16;
  __shared__ float Asum[ROWS0][132];
  __shared__ float Csum[ROWS0][132];

  const int t = threadIdx.x;
  const long blk = blockIdx.x;
  const int w = t >> 6, l = t & 63;
  const int a = l >> 4, fcol = l & 15, feat = w*16 + fcol;

  // ---- stage ----
  if constexpr (INPLANES){
    int row = t >> 4, c0 = (t & 15)*8;
    long base = (blk*ROWS0 + row)*(long)HH + c0;
    bf16x8 hv8 = *(const bf16x8*)&Hp[base];
    bf16x8 lv8 = *(const bf16x8*)&Lp[base];
#pragma unroll
    for (int j = 0; j < 8; ++j)
      Asum[row][c0+j] = bf16_to_f(((unsigned short*)&hv8)[j]) + bf16_to_f(((unsigned short*)&lv8)[j]);
    *(float4*)&Csum[row][c0]   = *(const float4*)&cs[base];
    *(float4*)&Csum[row][c0+4] = *(const float4*)&cs[base+4];
  } else {
    int row = t >> 3, c0 = (t & 7)*16;
    long g = (blk*2*ROWS0 + 2*row)*(long)HH + c0;
#pragma unroll
    for (int i = 0; i < 4; ++i){
      float4 x = *(const float4*)&hraw[g + 4*i];
      float4 y = *(const float4*)&hraw[g + HH + 4*i];
      float4 s; s.x=x.x+y.x; s.y=x.y+y.y; s.z=x.z+y.z; s.w=x.w+y.w;
      *(float4*)&Asum[row][c0 + 4*i] = s;
      float4 cx = *(const float4*)&craw[g + 4*i];
      float4 cy = *(const float4*)&craw[g + HH + 4*i];
      float4 cs4; cs4.x=cx.x+cy.x; cs4.y=cx.y+cy.y; cs4.z=cx.z+cy.z; cs4.w=cx.w+cy.w;
      *(float4*)&Csum[row][c0 + 4*i] = cs4;
    }
  }

  bf16x8 rbH[4][4], rbL[4][4];
#pragma unroll
  for (int q = 0; q < 4; ++q)
#pragma unroll
    for (int kc = 0; kc < 4; ++kc){
      long off = ((long)((((w>>1)*8) + q*2 + (w&1))*4 + kc)*64 + l)*8;
      rbH[q][kc] = *(const bf16x8*)&packH[off];
      rbL[q][kc] = *(const bf16x8*)&packL[off];
    }
  float B4[4];
#pragma unroll
  for (int q = 0; q < 4; ++q) B4[q] = bias[q*HH + feat];

  __syncthreads();

#pragma unroll
  for (int lv = 0; lv < NLEV; ++lv){
    const int rows  = ROWS0 >> lv;
    const int tiles = (rows >= 16) ? (rows/16) : 1;
    float hv[MT][4], cv[MT][4];

#pragma unroll
    for (int mt = 0; mt < MT; ++mt){
      if (mt >= tiles) continue;
      // A-build: RNE-hi / trunc-lo split from fp32 Asum
      bf16x8 aH[4], aL[4];
#pragma unroll
      for (int kc = 0; kc < 4; ++kc){
        const float* ap = &Asum[mt*16 + fcol][kc*32 + a*8];
        float av[8];
        *(float4*)&av[0] = *(const float4*)&ap[0];
        *(float4*)&av[4] = *(const float4*)&ap[4];
        unsigned int hp[4], lp[4];
#pragma unroll
        for (int p = 0; p < 4; ++p){
          unsigned int u0 = __float_as_uint(av[2*p]);
          unsigned int u1 = __float_as_uint(av[2*p+1]);
          unsigned int r0 = u0 + 0x7fffu + ((u0>>16)&1u);
          unsigned int r1 = u1 + 0x7fffu + ((u1>>16)&1u);
          float l0 = av[2*p]   - __uint_as_float(r0 & 0xffff0000u);
          float l1 = av[2*p+1] - __uint_as_float(r1 & 0xffff0000u);
          hp[p] = __builtin_amdgcn_perm(r1, r0, 0x07060302u);
          lp[p] = __builtin_amdgcn_perm(__float_as_uint(l1), __float_as_uint(l0), 0x07060302u);
        }
        uint4 hq = {hp[0], hp[1], hp[2], hp[3]};
        uint4 lq = {lp[0], lp[1], lp[2], lp[3]};
        aH[kc] = *(bf16x8*)&hq;
        aL[kc] = *(bf16x8*)&lq;
      }
      f32x4 acc[4];
#pragma unroll
      for (int q = 0; q < 4; ++q) acc[q] = (f32x4)(0.f);
#pragma unroll
      for (int kc = 0; kc < 4; ++kc){
#pragma unroll
        for (int q = 0; q < 4; ++q)
          acc[q] = __builtin_amdgcn_mfma_f32_16x16x32_bf16(aH[kc], rbH[q][kc], acc[q], 0, 0, 0);
#pragma unroll
        for (int q = 0; q < 4; ++q)
          acc[q] = __builtin_amdgcn_mfma_f32_16x16x32_bf16(aH[kc], rbL[q][kc], acc[q], 0, 0, 0);
#pragma unroll
        for (int q = 0; q < 4; ++q)
          acc[q] = __builtin_amdgcn_mfma_f32_16x16x32_bf16(aL[kc], rbH[q][kc], acc[q], 0, 0, 0);
      }
#pragma unroll
      for (int rr = 0; rr < 4; ++rr){
        int n = mt*16 + a*4 + rr;
        float ccv = Csum[n][feat];
        float fv = acc[0][rr] + B4[0];
        float iv = acc[1][rr] + B4[1];
        float gv = acc[2][rr] + B4[2];
        float ov = acc[3][rr] + B4[3];
        float c = sigf(fv)*ccv + sigf(iv)*tanhf_(gv);
        float h = sigf(ov)*tanhf_(c);
        hv[mt][rr] = h; cv[mt][rr] = c;
      }
    }
    __syncthreads();

    if (lv < NLEV-1){
#pragma unroll
      for (int mt = 0; mt < MT; ++mt){
        if (mt >= tiles) continue;
#pragma unroll
        for (int p = 0; p < 2; ++p){
          int n0 = mt*16 + a*4 + 2*p;
          if (n0 < rows){
            int prow = n0 >> 1;
            Asum[prow][feat] = hv[mt][2*p] + hv[mt][2*p+1];
            Csum[prow][feat] = cv[mt][2*p] + cv[mt][2*p+1];
          }
        }
      }
      __syncthreads();
    } else if (FINAL){
      if (a == 0) root_out[feat] = hv[0][0];
    } else {
      if (a == 0){
        h_out[blk*HH + feat] = hv[0][0];
        c_out[blk*HH + feat] = cv[0][0];
      }
    }
  }
}

extern "C" void kernel_launch(void* const* d_in, const int* in_sizes, int n_in,
                              void* d_out, int out_size, void* d_ws, size_t ws_size,
                              hipStream_t stream){
  const float* leaf = (const float*)d_in[0];   // 131072 x 128 f32
  const float* W    = (const float*)d_in[1];   // 512 x 256 f32
  const float* bias = (const float*)d_in[2];   // 512 f32
  float* out = (float*)d_out;                  // 128 f32

  // workspace layout
  unsigned short* pEh = (unsigned short*)d_ws;  // 65536 shorts each
  unsigned short* pEl = pEh + 65536;
  unsigned short* pLh = pEl + 65536;
  unsigned short* pLl = pLh + 65536;
  unsigned short* HpA = pLl + 65536;            // 2^16 x 128 bf16
  unsigned short* LpA = HpA + (long)(1<<16)*HH;
  unsigned short* HpB = LpA + (long)(1<<16)*HH; // 2^15 x 128 bf16
  unsigned short* LpB = HpB + (long)(1<<15)*HH;
  float* csA = (float*)(LpB + (long)(1<<15)*HH);// 2^16 x 128 f32
  float* csB = csA + (long)(1<<16)*HH;          // 2^15 x 128 f32
  float* h128 = csB + (long)(1<<15)*HH;         // 128 x 128 f32
  float* c128 = h128 + 128*HH;

  prep_pack<<<32, PT, 0, stream>>>(W, pEh, pEl, pLh, pLl);

  // leaf: 2^17 nodes -> 2^16 pair-rows
  leaf_mfma<<<GL, NT, 0, stream>>>(leaf, pLh, pLl, bias, HpA, LpA, csA, 4096);
  // internal levels (barrier-free): nodes 2^16, 2^15, 2^14, 2^13
  int_mfma<<<512, NT, 0, stream>>>(HpA, LpA, csA, pEh, pEl, bias, HpB, LpB, csB, 2048);
  int_mfma<<<512, NT, 0, stream>>>(HpB, LpB, csB, pEh, pEl, bias, HpA, LpA, csA, 1024);
  int_mfma<<<512, NT, 0, stream>>>(HpA, LpA, csA, pEh, pEl, bias, HpB, LpB, csB, 512);
  int_mfma<<<256, NT, 0, stream>>>(HpB, LpB, csB, pEh, pEl, bias, HpA, LpA, csA, 256);
  // tail: 2^12 pair-rows -> 128 nodes (6 levels/block) -> root (7 levels)
  treeblk2<32,6,1,0><<<128, NT, 0, stream>>>(HpA, LpA, csA, nullptr, nullptr,
                                             pEh, pEl, bias, h128, c128, nullptr);
  treeblk2<64,7,0,1><<<1, NT, 0, stream>>>(nullptr, nullptr, nullptr, h128, c128,
                                           pEh, pEl, bias, nullptr, nullptr, out);

  (void)in_sizes; (void)n_in; (void)out_size; (void)ws_size;
}